// Round 6
// baseline (860.793 us; speedup 1.0000x reference)
//
#include <hip/hip_runtime.h>
#include <hip/hip_bf16.h>
#include <stdint.h>

// ---------------------------------------------------------------------------
// LinearSelfAttention (Performer-style) on gfx950.
//   pre:  pos/slp -> f16 [hi|lo] (one launch, aliased onto qpr/kpr), x -> f16
//   V     = x16 @ W_v                   (f16 MFMA, global_load_lds staging)
//   P|S   = pos/slp @ W_pf              (pre-split f16, virtual K=3072, one
//           dispatch z=2; epilogue writes f16 [hi|lo] pairs Pb2/Sb2 + norms)
//   q',k' = split two-z-slice fourier: q K=192 {Ph,Pl,Ph}, k K=384 adds
//           {Sh,Sl,Sh} from Pb2+sAb; sin/cos EPI.
//   kvT   = sum_l v[l][d] k'[l][m]      (f16 MFMA, reg-transpose + XOR LDS)
//   z     = q'' @ kvT                   (batched f16 MFMA; B staged straight
//           from f32 kvacc with reg-cast)
//   out   = z @ W_o                     (f16 MFMA, f32 out)
// R9 basis: R5's 64-bit per-lane pointer hoisting regressed P|S 147->166
// (vaddr-64 global_load_lds + v_addc chains). Fix: hoist 32-BIT offsets
// (int aoff/boff) + int section offset cb -> compiler keeps saddr form
// (SGPR base + 32-bit voffset), one v_add per load in the k-loop.
// Workspace ~216.6 MB.
// ---------------------------------------------------------------------------

typedef _Float16 hx8 __attribute__((ext_vector_type(8)));
typedef _Float16 hx4 __attribute__((ext_vector_type(4)));
typedef float    fx4 __attribute__((ext_vector_type(4)));

#define H_   16
#define D_   64
#define L_   4096
#define B_   4
#define KV_SPLIT 16

// global -> LDS direct (16B/lane). LDS dest wave-uniform; HW adds lane*16.
__device__ __forceinline__ void g2l16(const _Float16* g, _Float16* l) {
  __builtin_amdgcn_global_load_lds(
      (const __attribute__((address_space(1))) void*)g,
      (__attribute__((address_space(3))) void*)l, 16, 0, 0);
}

// ---------------- prep kernels ----------------
// two W [1024][1024] f32 -> WT f16 transposes in one launch (z selects)
__global__ __launch_bounds__(256) void wt2_k(const float* __restrict__ W0,
                                             _Float16* __restrict__ T0,
                                             const float* __restrict__ W1,
                                             _Float16* __restrict__ T1) {
  const float* W = blockIdx.z ? W1 : W0;
  _Float16* WT   = blockIdx.z ? T1 : T0;
  __shared__ float tile[64][65];
  int t = threadIdx.x; int c = t & 63; int r0 = t >> 6;
  int bx = blockIdx.x * 64, by = blockIdx.y * 64;
  for (int r = r0; r < 64; r += 4) tile[r][c] = W[(long)(by + r) * 1024 + bx + c];
  __syncthreads();
  for (int r = r0; r < 64; r += 4)
    WT[(long)(bx + r) * 1024 + by + c] = (_Float16)tile[c][r];
}

// W_pf -> WT3 [1024][3072] f16 sections: [hi ; hi ; lo] (transposed)
__global__ __launch_bounds__(256) void wpf3_k(const float* __restrict__ W,
                                              _Float16* __restrict__ WT3) {
  __shared__ float tile[64][65];
  int t = threadIdx.x; int c = t & 63; int r0 = t >> 6;
  int bx = blockIdx.x * 64, by = blockIdx.y * 64;
  for (int r = r0; r < 64; r += 4) tile[r][c] = W[(long)(by + r) * 1024 + bx + c];
  __syncthreads();
  for (int r = r0; r < 64; r += 4) {
    float x = tile[c][r];
    _Float16 hi = (_Float16)x;
    _Float16 lo = (_Float16)(x - (float)hi);
    long base = (long)(bx + r) * 3072 + by + c;
    WT3[base] = hi; WT3[base + 1024] = hi; WT3[base + 2048] = lo;
  }
}

// proj [128][64] f32 -> proj6T [128][384] f16 [hi|hi|lo|hi|hi|lo], cnorm folded
__global__ __launch_bounds__(256) void proj6_k(const float* __restrict__ proj,
                                               _Float16* __restrict__ proj6T) {
  int i = blockIdx.x * 256 + threadIdx.x;
  if (i >= 8192) return;
  int m = i >> 6, d = i & 63;
  float p = 0.35355339059327373f * proj[i];    // 1/64^0.25 folded
  _Float16 hi = (_Float16)p;
  _Float16 lo = (_Float16)(p - (float)hi);
  long b = (long)m * 384 + d;
  proj6T[b]       = hi; proj6T[b + 64]  = hi; proj6T[b + 128] = lo;
  proj6T[b + 192] = hi; proj6T[b + 256] = hi; proj6T[b + 320] = lo;
}

__global__ __launch_bounds__(256) void zero_k(float* __restrict__ p, int n4) {
  int i = blockIdx.x * 256 + threadIdx.x;
  int stride = gridDim.x * 256;
  fx4 z = {0.f, 0.f, 0.f, 0.f};
  for (; i < n4; i += stride) ((fx4*)p)[i] = z;
}

// [8192][1024] f32 -> [8192][2048] f16 [hi|lo]; grid.y picks pos/slp.
__global__ __launch_bounds__(256) void cvt_hilo2_k(const float* __restrict__ pos,
                                                   const float* __restrict__ slp,
                                                   _Float16* __restrict__ ph2,
                                                   _Float16* __restrict__ sh2) {
  const float* in = blockIdx.y ? slp : pos;
  _Float16* out   = blockIdx.y ? sh2 : ph2;
  long i = (long)blockIdx.x * 256 + threadIdx.x;
  long idx = i * 8;
  int row = (int)(idx >> 10), c = (int)(idx & 1023);
  fx4 a = *(const fx4*)&in[idx];
  fx4 b = *(const fx4*)&in[idx + 4];
  hx8 hi, lo;
#pragma unroll
  for (int e = 0; e < 4; ++e) {
    _Float16 h0 = (_Float16)a[e]; hi[e] = h0;     lo[e]     = (_Float16)(a[e] - (float)h0);
    _Float16 h1 = (_Float16)b[e]; hi[4 + e] = h1; lo[4 + e] = (_Float16)(b[e] - (float)h1);
  }
  *(hx8*)&out[(long)row * 2048 + c]        = hi;
  *(hx8*)&out[(long)row * 2048 + 1024 + c] = lo;
}

// plain f32 -> f16 cast, 8/thread vectorized
__global__ __launch_bounds__(256) void cvt16_k(const float* __restrict__ in,
                                               _Float16* __restrict__ out, long n8) {
  long i = (long)blockIdx.x * 256 + threadIdx.x;
  if (i >= n8) return;
  long idx = i * 8;
  fx4 a = *(const fx4*)&in[idx];
  fx4 b = *(const fx4*)&in[idx + 4];
  hx8 h;
#pragma unroll
  for (int e = 0; e < 4; ++e) { h[e] = (_Float16)a[e]; h[4 + e] = (_Float16)b[e]; }
  *(hx8*)&out[idx] = h;
}

// ---------------- generic f16 MFMA GEMM:  C[M][N] = A[M][K] @ BT[N][K]^T ----
// BK=64, 256 threads, 4 waves 2x2; XOR-swizzled LDS (conflict-free b128).
// Staging offsets hoisted as 32-BIT ints (saddr form preserved): per-thread
// row = i*32 + (t>>3), kc = (t&7)^((t>>3)&7) are k0-invariant.
// AMODE: 0 = A f16 gload_lds;
//        4 = A f16 pre-split [hi|lo] (lda=2*(1<<SECSH)), gload_lds,
//            section map k0 -> {hi, lo, hi};
//        5 = fourier A: f16 [hi64|lo64] rows (lda=128), SECSH=6 sections
//            {Ph,Pl,Ph,Sh,Sl,Sh}; S-buffer at A16+sAb; q-side (bz&1==0)
//            runs only K/2 (first 3 sections).
// BMODE: 0 = B f16 gload_lds; 1 = B f32 (reg-cast staging; ldb/sB* in f32).
// EPI: 0 plain store | 1 fourier sin/cos (norms if (bz&15)==0) |
//      4 fused P|S: bz==0 -> Pb2 f16 hi|lo = scp[h]*acc; bz==1 -> A=Pprev,
//        Sb2(+sCh) f16 hi|lo = ofp[h]*scp[h]*acc, nout = ||acc_row||/L.
template<int BM, int BN, int AMODE, int SECSH, int EPI, int BMODE, typename OUT_T>
__global__ __launch_bounds__(256) void gemm_bt_k(
    const void* __restrict__ Av, const _Float16* __restrict__ BT,
    OUT_T* __restrict__ C, int K, int lda, int ldb, int ldc,
    long sAb, long sAh, long sBb, long sBh, long sCb, long sCh,
    const float* __restrict__ norms, const float* __restrict__ scp,
    const float* __restrict__ ofp, const float* __restrict__ Pprev,
    float* __restrict__ nout)
{
  __shared__ __align__(16) _Float16 sA[BM * 64];
  __shared__ __align__(16) _Float16 sB[BN * 64];
  const int t = threadIdx.x;
  const int lane = t & 63;
  const int w = t >> 6;
  const int wm = w >> 1, wn = w & 1;
  const int by = blockIdx.x, bx = blockIdx.y, bz = blockIdx.z;
  long aoff64 = (long)(bz >> 4) * sAb + (long)(bz & 15) * sAh;
  if constexpr (AMODE == 5) aoff64 = 0;   // sAb reused as S-buffer offset
  const _Float16* BT16 = BT;
  const float*    B32  = (const float*)BT;
  if constexpr (BMODE == 0) BT16 += (long)(bz >> 4) * sBb + (long)(bz & 15) * sBh;
  else                      B32  += (long)(bz >> 4) * sBb + (long)(bz & 15) * sBh;
  C += (long)(bz >> 4) * sCb + (long)(bz & 15) * sCh;
  const _Float16* A16 = (const _Float16*)Av + aoff64;
  if constexpr (EPI == 4) {               // fused P|S: z=1 reads slopes side
    if (bz & 15) A16 = (const _Float16*)Pprev + aoff64;
  }
  constexpr int WTM = BM / 32, WTN = BN / 32;
  fx4 acc[WTM][WTN];
#pragma unroll
  for (int i = 0; i < WTM; ++i)
#pragma unroll
    for (int j = 0; j < WTN; ++j) acc[i][j] = (fx4){0.f, 0.f, 0.f, 0.f};

  // ---- hoisted 32-bit staging offsets (k0-invariant) ----
  const int trow = t >> 3;                     // 0..31
  const int kc8  = ((t & 7) ^ (trow & 7)) * 8; // element offset within row
  int aoff[BM / 32];
#pragma unroll
  for (int i = 0; i < BM / 32; ++i)
    aoff[i] = (by * BM + i * 32 + trow) * lda + kc8;
  int boff[BN / 32];
#pragma unroll
  for (int i = 0; i < BN / 32; ++i)
    boff[i] = (bx * BN + i * 32 + trow) * ldb + kc8;
  // LDS dest slots (wave-uniform base per i; HW adds lane*16)
  _Float16* sAdst[BM / 32];
  _Float16* sBdst[BN / 32];
#pragma unroll
  for (int i = 0; i < BM / 32; ++i) sAdst[i] = &sA[(i * 256 + (w << 6)) * 8];
#pragma unroll
  for (int i = 0; i < BN / 32; ++i) sBdst[i] = &sB[(i * 256 + (w << 6)) * 8];

  int Klim = K;
  if constexpr (AMODE == 5) { if ((bz & 1) == 0) Klim >>= 1; }

  for (int k0 = 0; k0 < Klim; k0 += 64) {
    __syncthreads();
    // ---- stage A tile [BM x 64] via global_load_lds (saddr + 32b voffset) --
    {
      int cb;
      if constexpr (AMODE == 4) {
        int sec = k0 >> SECSH;
        cb = (k0 & ((1 << SECSH) - 1)) + (sec == 1 ? (1 << SECSH) : 0);
      } else if constexpr (AMODE == 5) {
        int sec = k0 >> SECSH;
        cb = ((sec == 1 || sec == 4) ? 64 : 0) + (sec >= 3 ? (int)sAb : 0);
      } else cb = k0;
#pragma unroll
      for (int i = 0; i < BM / 32; ++i) g2l16(A16 + (aoff[i] + cb), sAdst[i]);
    }
    // ---- stage B tile [BN x 64] ----
    if constexpr (BMODE == 0) {
#pragma unroll
      for (int i = 0; i < BN / 32; ++i) g2l16(BT16 + (boff[i] + k0), sBdst[i]);
    } else {
#pragma unroll
      for (int i = 0; i < BN / 32; ++i) {
        const float* src = B32 + (boff[i] + k0);
        fx4 v0 = *(const fx4*)src;
        fx4 v1 = *(const fx4*)(src + 4);
        hx8 hv;
#pragma unroll
        for (int e = 0; e < 4; ++e) { hv[e] = (_Float16)v0[e]; hv[4 + e] = (_Float16)v1[e]; }
        *(hx8*)&sB[(i * 256 + t) * 8] = hv;
      }
    }
    __syncthreads();
#pragma unroll
    for (int kk = 0; kk < 64; kk += 32) {
      hx8 af[WTM], bf[WTN];
      int kcb = (kk >> 3) + (lane >> 4);
#pragma unroll
      for (int i = 0; i < WTM; ++i) {
        int r = wm * (BM / 2) + i * 16 + (lane & 15);
        af[i] = *(const hx8*)&sA[(r * 8 + (kcb ^ (r & 7))) * 8];
      }
#pragma unroll
      for (int j = 0; j < WTN; ++j) {
        int r = wn * (BN / 2) + j * 16 + (lane & 15);
        bf[j] = *(const hx8*)&sB[(r * 8 + (kcb ^ (r & 7))) * 8];
      }
#pragma unroll
      for (int i = 0; i < WTM; ++i)
#pragma unroll
        for (int j = 0; j < WTN; ++j)
          acc[i][j] = __builtin_amdgcn_mfma_f32_16x16x32_f16(af[i], bf[j], acc[i][j], 0, 0, 0);
    }
  }
  if constexpr (EPI == 0) {
#pragma unroll
    for (int i = 0; i < WTM; ++i) {
#pragma unroll
      for (int j = 0; j < WTN; ++j) {
        int rowb = by * BM + wm * (BM / 2) + i * 16 + ((lane >> 4) << 2);
        int col  = bx * BN + wn * (BN / 2) + j * 16 + (lane & 15);
#pragma unroll
        for (int r = 0; r < 4; ++r)
          C[(long)(rowb + r) * ldc + col] = (OUT_T)acc[i][j][r];
      }
    }
  } else if constexpr (EPI == 1) {
    const float inv2pi = 0.15915494309189535f;
    const float ratio  = 0.08838834764831845f;   // 1/sqrt(128)
    const bool useN = ((bz & 15) == 0);
#pragma unroll
    for (int i = 0; i < WTM; ++i) {
#pragma unroll
      for (int j = 0; j < WTN; ++j) {
        int rowb = by * BM + wm * (BM / 2) + i * 16 + ((lane >> 4) << 2);
        int col  = bx * BN + wn * (BN / 2) + j * 16 + (lane & 15);
#pragma unroll
        for (int r = 0; r < 4; ++r) {
          int row = rowb + r;                     // row = l*16 + h
          float rn = ratio * (useN ? norms[row] : 1.0f);
          long ob = ((long)(row & 15) * 4096 + (row >> 4)) * 256;
          float v = acc[i][j][r] * inv2pi;
          v -= floorf(v);                         // revolutions in [0,1)
          C[ob + col]       = (OUT_T)(rn * __builtin_amdgcn_sinf(v));
          C[ob + 128 + col] = (OUT_T)(rn * __builtin_amdgcn_cosf(v));
        }
      }
    }
  } else {                                // EPI == 4: fused P|S, f16 hi|lo out
    const int h = ((bx * BN) >> 6) + wn;  // BN=128: 2 heads/block, wave-uniform
    const float sc = scp[h];
    _Float16* C16 = (_Float16*)C;
    if ((bz & 15) == 0) {                 // P: Pb2 = hi|lo of scale*acc
#pragma unroll
      for (int i = 0; i < WTM; ++i) {
#pragma unroll
        for (int j = 0; j < WTN; ++j) {
          int rowb = by * BM + wm * (BM / 2) + i * 16 + ((lane >> 4) << 2);
          int d    = j * 16 + (lane & 15);
#pragma unroll
          for (int r = 0; r < 4; ++r) {
            float v = sc * acc[i][j][r];
            long a = ((long)(rowb + r) * 16 + h) * 128 + d;
            _Float16 hi = (_Float16)v;
            C16[a]      = hi;
            C16[a + 64] = (_Float16)(v - (float)hi);
          }
        }
      }
    } else {                              // S: Sb2 = hi|lo of offs*scale*acc
      const float osc = ofp[h] * sc;
#pragma unroll
      for (int i = 0; i < WTM; ++i) {
        float sq[4] = {0.f, 0.f, 0.f, 0.f};
        int rowb = by * BM + wm * (BM / 2) + i * 16 + ((lane >> 4) << 2);
#pragma unroll
        for (int j = 0; j < WTN; ++j) {
          int d = j * 16 + (lane & 15);
#pragma unroll
          for (int r = 0; r < 4; ++r) {
            float a0 = acc[i][j][r];
            sq[r] += a0 * a0;
            float v = osc * a0;
            long a = ((long)(rowb + r) * 16 + h) * 128 + d;
            _Float16 hi = (_Float16)v;
            C16[a]      = hi;
            C16[a + 64] = (_Float16)(v - (float)hi);
          }
        }
#pragma unroll
        for (int r = 0; r < 4; ++r) {     // 64-col norm: 4 j's x 16 lanes
          float s = sq[r];
          s += __shfl_xor(s, 1); s += __shfl_xor(s, 2);
          s += __shfl_xor(s, 4); s += __shfl_xor(s, 8);
          if ((lane & 15) == 0)
            nout[(long)(rowb + r) * 16 + h] = sqrtf(s) * (1.0f / 4096.0f);
        }
      }
    }
  }
}

// ---------------- kv kernel (per-b): kvT[d][m] = sum_l v[l][d] * k'[l][m] ---
// Staging: 4x8 register transpose -> ds_write_b64, XOR bank-swizzle.
__global__ __launch_bounds__(256) void kv_k(const _Float16* __restrict__ Kp,
                                            const _Float16* __restrict__ Vhb,
                                            float* __restrict__ kvacc)
{
  __shared__ __align__(16) _Float16 sK[256 * 72];   // [m][l] stride 72, swizzled
  __shared__ __align__(16) _Float16 sV[64 * 72];    // [d][l]
  const int t = threadIdx.x, lane = t & 63, w = t >> 6;
  const int h = blockIdx.x;
  const int l0 = blockIdx.y * (L_ / KV_SPLIT);
  fx4 acc[4][4];
#pragma unroll
  for (int i = 0; i < 4; ++i)
#pragma unroll
    for (int j = 0; j < 4; ++j) acc[i][j] = (fx4){0.f, 0.f, 0.f, 0.f};
  const _Float16* Kbase = Kp + (long)h * L_ * 256;
  for (int kt = 0; kt < L_ / KV_SPLIT; kt += 64) {
    __syncthreads();
    // k' tile: 64 l x 256 m. 512 items (m8, l4), 2 per thread.
#pragma unroll
    for (int it = 0; it < 2; ++it) {
      int idx = t + it * 256;
      int m8 = idx & 31, bl = (idx >> 5) << 2;
      const _Float16* src = &Kbase[(long)(l0 + kt + bl) * 256 + m8 * 8];
      hx8 r0 = *(const hx8*)(src);
      hx8 r1 = *(const hx8*)(src + 256);
      hx8 r2 = *(const hx8*)(src + 512);
      hx8 r3 = *(const hx8*)(src + 768);
      int kx = (m8 & 7) << 4;
#pragma unroll
      for (int e = 0; e < 8; ++e) {
        hx4 v; v[0] = r0[e]; v[1] = r1[e]; v[2] = r2[e]; v[3] = r3[e];
        int byte = (((m8 * 8 + e) * 72 + bl) * 2) ^ kx;
        *(hx4*)((char*)sK + byte) = v;
      }
    }
    // v tile: 64 l x 64 d. 128 items, threads t<128.
    if (t < 128) {
      int d8 = t & 7, bl = (t >> 3) << 2;
      const _Float16* src = &Vhb[(long)(l0 + kt + bl) * 1024 + h * 64 + d8 * 8];
      hx8 r0 = *(const hx8*)(src);
      hx8 r1 = *(const hx8*)(src + 1024);
      hx8 r2 = *(const hx8*)(src + 2048);
      hx8 r3 = *(const hx8*)(src + 3072);
      int kx = d8 << 4;
#pragma unroll
      for (int e = 0; e < 8; ++e) {
        hx4 v; v[0] = r0[e]; v[1] = r1[e]; v[2] = r2[e]; v[3] = r3[e];
        int byte = (((d8 * 8 + e) * 72 + bl) * 2) ^ kx;
        *(hx4*)((char*)sV + byte) = v;
      }
    }
    __syncthreads();
#pragma unroll
    for (int kk = 0; kk < 64; kk += 32) {
      hx8 af[4], bf[4];
      int lfr = kk + ((lane >> 4) << 3);
#pragma unroll
      for (int i = 0; i < 4; ++i) {
        int r = i * 16 + (lane & 15);
        af[i] = *(const hx8*)((const char*)sV +
                ((((r * 72 + lfr) * 2)) ^ (((r >> 3) & 7) << 4)));
      }
#pragma unroll
      for (int j = 0; j < 4; ++j) {
        int r = w * 64 + j * 16 + (lane & 15);
        bf[j] = *(const hx8*)((const char*)sK +
                ((((r * 72 + lfr) * 2)) ^ (((r >> 3) & 7) << 4)));
      }
#pragma unroll
      for (int i = 0; i < 4; ++i)
#pragma unroll
        for (int j = 0; j < 4; ++j)
          acc[i][j] = __builtin_amdgcn_mfma_f32_16x16x32_f16(af[i], bf[j], acc[i][j], 0, 0, 0);
    }
  }
  float* obase = kvacc + (long)h * (64 * 256);
#pragma unroll
  for (int i = 0; i < 4; ++i)
#pragma unroll
    for (int j = 0; j < 4; ++j) {
      int d0 = i * 16 + ((lane >> 4) << 2);
      int m  = w * 64 + j * 16 + (lane & 15);
#pragma unroll
      for (int r = 0; r < 4; ++r)
        atomicAdd(&obase[(long)(d0 + r) * 256 + m], acc[i][j][r]);
    }
}

// ---------------------------------------------------------------------------
extern "C" void kernel_launch(void* const* d_in, const int* in_sizes, int n_in,
                              void* d_out, int out_size, void* d_ws, size_t ws_size,
                              hipStream_t stream) {
  const float* x     = (const float*)d_in[0];
  const float* pos   = (const float*)d_in[1];
  const float* slp   = (const float*)d_in[2];
  const float* Wv    = (const float*)d_in[3];
  const float* Wo    = (const float*)d_in[4];
  const float* Wpf   = (const float*)d_in[5];
  const float* scale = (const float*)d_in[6];
  const float* offs  = (const float*)d_in[7];
  const float* proj  = (const float*)d_in[8];
  float* out = (float*)d_out;
  char* ws = (char*)d_ws;

  // Arena ~216.6 MB. Aliases (stream-order-safe):
  //   ph2 = qpr, sh2 = kpr  (f16 [hi|lo] pos/slp; consumed by P|S before
  //   fourier overwrites qpr/kpr);  xh = Zb (consumed by V before z).
  // NOTE: Sb2 must follow Pb2 contiguously (+16777216 f16); kpr follows qpr.
  size_t o = 0;
  auto alloc = [&](size_t bytes) { char* p = ws + o; o += (bytes + 255) & ~(size_t)255; return p; };
  _Float16* Pb2    = (_Float16*)alloc(33554432);   // [2b][65536 lh][128 hi|lo] f16
  _Float16* Sb2    = (_Float16*)alloc(33554432);   //   == Pb2 + 16777216
  _Float16* qpr    = (_Float16*)alloc(33554432);   // per-b [H][L][256] f16
  _Float16* kpr    = (_Float16*)alloc(33554432);   //   == qpr + 16777216
  _Float16* Vh     = (_Float16*)alloc(33554432);   // [BL][1024] f16
  _Float16* Zb     = (_Float16*)alloc(33554432);   // [BL][1024] f16
  _Float16* WvT    = (_Float16*)alloc(2097152);
  _Float16* WoT    = (_Float16*)alloc(2097152);
  _Float16* Wpf3T  = (_Float16*)alloc(6291456);    // [1024][3072] [hi;hi;lo]
  _Float16* proj6T = (_Float16*)alloc(98304);      // [128][384] [hi|hi|lo|hi|hi|lo]
  float*    normsB = (float*)alloc(524288);        // [8192][16] f32 per super-batch
  float*    kvacc  = (float*)alloc(4194304);       // [BH][64][256] f32
  _Float16* ph2 = qpr;                             // [8192][2048] f16 [hi|lo]
  _Float16* sh2 = kpr;
  _Float16* xh  = Zb;                              // [16384][1024] f16
  (void)Sb2; (void)ws_size; (void)in_sizes; (void)n_in; (void)out_size;

  // prep (5 launches)
  wt2_k<<<dim3(16, 16, 2), 256, 0, stream>>>(Wv, WvT, Wo, WoT);
  wpf3_k<<<dim3(16, 16), 256, 0, stream>>>(Wpf, Wpf3T);
  proj6_k<<<32, 256, 0, stream>>>(proj, proj6T);
  zero_k<<<256, 256, 0, stream>>>(kvacc, 1048576 / 4);
  cvt16_k<<<8192, 256, 0, stream>>>(x, xh, 2097152);

  // V = xh @ W_v (pure f16, gload_lds staging), M=16384, grid (M,N)-swapped
  gemm_bt_k<128, 128, 0, 0, 0, 0, _Float16><<<dim3(128, 8, 1), 256, 0, stream>>>(
      xh, WvT, Vh, 1024, 1024, 1024, 1024, 0, 0, 0, 0, 0, 0,
      nullptr, nullptr, nullptr, nullptr, nullptr);

  for (int sb = 0; sb < 2; ++sb) {
    const float* pos_sb = pos + (long)sb * 8192 * 1024;
    const float* slp_sb = slp + (long)sb * 8192 * 1024;
    // pre-split pos+slp to f16 [hi|lo] in one launch
    cvt_hilo2_k<<<dim3(4096, 2), 256, 0, stream>>>(pos_sb, slp_sb, ph2, sh2);
    // Fused P|S: z=0 -> Pb2 = hilo(scale*(pos@W)); z=1 -> Sb2 =
    // hilo(offs*scale*(slp@W)) + slope norms. AMODE=4, virtual K=3072.
    gemm_bt_k<128, 128, 4, 10, 4, 0, _Float16><<<dim3(64, 8, 2), 256, 0, stream>>>(
        ph2, Wpf3T, Pb2, 3072, 2048, 3072, 128, 0, 0, 0, 0, 0, 16777216L,
        nullptr, scale, offs, (const float*)sh2, normsB);

    for (int bb = 0; bb < 2; ++bb) {
      int b = sb * 2 + bb;
      _Float16* Vh_b  = Vh + (long)b * L_ * 1024;
      _Float16* Zb_b  = Zb + (long)b * L_ * 1024;
      float* kvacc_b  = kvacc + (long)b * H_ * 64 * 256;
      // split fourier: bz=0 q-side K=192 {Ph,Pl,Ph} + norms; bz=1 k-side
      // K=384 adds {Sh,Sl,Sh} from Pb2+sAb. 1024 blocks.
      gemm_bt_k<128, 128, 5, 6, 1, 0, _Float16><<<dim3(512, 1, 2), 256, 0, stream>>>(
          Pb2 + (long)bb * 8388608, proj6T, qpr, 384, 128, 384, 0,
          16777216L /*S-buffer offset*/, 0L, 0, 0, 0, 16777216L,
          normsB + (long)bb * 65536, nullptr, nullptr, nullptr, nullptr);
      // kv (split-K=16 over L with atomics) -> kvacc_b (f32)
      kv_k<<<dim3(16, KV_SPLIT), 256, 0, stream>>>(kpr, Vh_b, kvacc_b);
      // z = q'' @ kvT (batched over h); B staged from f32 kvacc (BMODE=1)
      gemm_bt_k<128, 64, 0, 0, 0, 1, _Float16><<<dim3(32, 1, 16), 256, 0, stream>>>(
          qpr, (const _Float16*)kvacc_b, Zb_b, 256, 256, 256, 1024,
          0L, (long)L_ * 256, 0L, 16384L, 0L, 64L,
          nullptr, nullptr, nullptr, nullptr, nullptr);
    }
  }
  // out = z @ W_o (f32 out), M=16384
  gemm_bt_k<128, 128, 0, 0, 0, 0, float><<<dim3(128, 8, 1), 256, 0, stream>>>(
      Zb, WoT, out, 1024, 1024, 1024, 1024, 0, 0, 0, 0, 0, 0,
      nullptr, nullptr, nullptr, nullptr, nullptr);
}

// Round 7
// 846.640 us; speedup vs baseline: 1.0167x; 1.0167x over previous
//
#include <hip/hip_runtime.h>
#include <hip/hip_bf16.h>
#include <stdint.h>

// ---------------------------------------------------------------------------
// LinearSelfAttention (Performer-style) on gfx950.
//   prep  = ONE kernel: WvT/WoT transposes, Wpf3T, proj6T, kvacc zero, x->f16
//   V     = x16 @ W_v                   (f16 MFMA, global_load_lds staging)
//   P|S   = pos/slp @ W_pf              (pre-split f16, virtual K=3072, one
//           dispatch z=2; epilogue writes f16 [hi|lo] pairs Pb2/Sb2 + norms)
//   q',k' = fourier vs proj6T; BATCHED across bb (grid z=4: bz>>1 = bb,
//           bz&1 = q/k). q K=192 {Ph,Pl,Ph}, k K=384 adds {Sh,Sl,Sh}.
//   kvT   = sum_l v[l][d] k'[l][m]      (f16 MFMA; batched z=2 over bb)
//   z     = q'' @ kvT                   (batched z=32: bb x h; B from f32 kvacc)
//   out   = z @ W_o                     (f16 MFMA, f32 out)
// R10 basis: R6 showed per-kernel sums ~640us vs 861 measured -> ~200us is
// launch boundaries (23 dispatches). This round: 23 -> 14 dispatches via
// prep merge + bb-batching. bb-batching needs qpr/kpr x2 (+67MB -> ~284MB),
// runtime-gated on ws_size with exact-R6 fallback (graph-capture safe:
// branch resolves at capture).
// ---------------------------------------------------------------------------

typedef _Float16 hx8 __attribute__((ext_vector_type(8)));
typedef _Float16 hx4 __attribute__((ext_vector_type(4)));
typedef float    fx4 __attribute__((ext_vector_type(4)));

#define H_   16
#define D_   64
#define L_   4096
#define B_   4
#define KV_SPLIT 16

// global -> LDS direct (16B/lane). LDS dest wave-uniform; HW adds lane*16.
__device__ __forceinline__ void g2l16(const _Float16* g, _Float16* l) {
  __builtin_amdgcn_global_load_lds(
      (const __attribute__((address_space(1))) void*)g,
      (__attribute__((address_space(3))) void*)l, 16, 0, 0);
}

// ---------------- merged prep kernel ----------------
// blocks 0..255: WvT transpose | 256..511: WoT | 512..767: Wpf3T [hi;hi;lo]
// 768..799: proj6T | 800..1055: kvacc zero | 1056..9247: x -> f16
__global__ __launch_bounds__(256) void prep_k(
    const float* __restrict__ Wv, _Float16* __restrict__ WvT,
    const float* __restrict__ Wo, _Float16* __restrict__ WoT,
    const float* __restrict__ Wpf, _Float16* __restrict__ Wpf3T,
    const float* __restrict__ proj, _Float16* __restrict__ proj6T,
    float* __restrict__ kvacc, const float* __restrict__ x,
    _Float16* __restrict__ xh)
{
  __shared__ float tile[64][65];
  const int blk = blockIdx.x, t = threadIdx.x;
  if (blk < 768) {                       // three 64x64-tile transposes
    const float* W; int i;
    if (blk < 256)      { W = Wv;  i = blk; }
    else if (blk < 512) { W = Wo;  i = blk - 256; }
    else                { W = Wpf; i = blk - 512; }
    int bx = (i & 15) * 64, by = (i >> 4) * 64;
    int c = t & 63, r0 = t >> 6;
    for (int r = r0; r < 64; r += 4)
      tile[r][c] = W[(long)(by + r) * 1024 + bx + c];
    __syncthreads();
    if (blk < 512) {
      _Float16* WT = (blk < 256) ? WvT : WoT;
      for (int r = r0; r < 64; r += 4)
        WT[(long)(bx + r) * 1024 + by + c] = (_Float16)tile[c][r];
    } else {
      for (int r = r0; r < 64; r += 4) {
        float xv = tile[c][r];
        _Float16 hi = (_Float16)xv;
        _Float16 lo = (_Float16)(xv - (float)hi);
        long base = (long)(bx + r) * 3072 + by + c;
        Wpf3T[base] = hi; Wpf3T[base + 1024] = hi; Wpf3T[base + 2048] = lo;
      }
    }
  } else if (blk < 800) {                // proj6T
    int i = (blk - 768) * 256 + t;
    if (i < 8192) {
      float p = 0.35355339059327373f * proj[i];   // 1/64^0.25 folded
      _Float16 hi = (_Float16)p;
      _Float16 lo = (_Float16)(p - (float)hi);
      long b = (long)(i >> 6) * 384 + (i & 63);
      proj6T[b]       = hi; proj6T[b + 64]  = hi; proj6T[b + 128] = lo;
      proj6T[b + 192] = hi; proj6T[b + 256] = hi; proj6T[b + 320] = lo;
    }
  } else if (blk < 1056) {               // zero kvacc (262144 fx4)
    fx4 z = {0.f, 0.f, 0.f, 0.f};
#pragma unroll
    for (int e = 0; e < 4; ++e)
      ((fx4*)kvacc)[(blk - 800) * 1024 + e * 256 + t] = z;
  } else {                               // x -> f16 (2097152 x 8)
    long i = (long)(blk - 1056) * 256 + t;
    long idx = i * 8;
    fx4 a = *(const fx4*)&x[idx];
    fx4 b = *(const fx4*)&x[idx + 4];
    hx8 h;
#pragma unroll
    for (int e = 0; e < 4; ++e) { h[e] = (_Float16)a[e]; h[4 + e] = (_Float16)b[e]; }
    *(hx8*)&xh[idx] = h;
  }
}

// [8192][1024] f32 -> [8192][2048] f16 [hi|lo]; grid.y picks pos/slp.
__global__ __launch_bounds__(256) void cvt_hilo2_k(const float* __restrict__ pos,
                                                   const float* __restrict__ slp,
                                                   _Float16* __restrict__ ph2,
                                                   _Float16* __restrict__ sh2) {
  const float* in = blockIdx.y ? slp : pos;
  _Float16* out   = blockIdx.y ? sh2 : ph2;
  long i = (long)blockIdx.x * 256 + threadIdx.x;
  long idx = i * 8;
  int row = (int)(idx >> 10), c = (int)(idx & 1023);
  fx4 a = *(const fx4*)&in[idx];
  fx4 b = *(const fx4*)&in[idx + 4];
  hx8 hi, lo;
#pragma unroll
  for (int e = 0; e < 4; ++e) {
    _Float16 h0 = (_Float16)a[e]; hi[e] = h0;     lo[e]     = (_Float16)(a[e] - (float)h0);
    _Float16 h1 = (_Float16)b[e]; hi[4 + e] = h1; lo[4 + e] = (_Float16)(b[e] - (float)h1);
  }
  *(hx8*)&out[(long)row * 2048 + c]        = hi;
  *(hx8*)&out[(long)row * 2048 + 1024 + c] = lo;
}

// ---------------- generic f16 MFMA GEMM:  C[M][N] = A[M][K] @ BT[N][K]^T ----
// BK=64, 256 threads, 4 waves 2x2; XOR-swizzled LDS (conflict-free b128).
// Staging offsets hoisted as 32-bit ints (saddr form preserved).
// AMODE: 0 = A f16 gload_lds;
//        4 = A f16 pre-split [hi|lo] (lda=2*(1<<SECSH)), gload_lds,
//            section map k0 -> {hi, lo, hi};
//        5 = fourier A: f16 [hi64|lo64] rows (lda=128), SECSH=6 sections
//            {Ph,Pl,Ph,Sh,Sl,Sh}; S-buffer at +sAb; per-bb stride sAh via
//            (bz>>1); q-side (bz&1==0) runs only K/2.
// BMODE: 0 = B f16 gload_lds; 1 = B f32 (reg-cast staging).
// EPI: 0 plain store | 1 fourier sin/cos (norms if (bz&1)==0, +((bz>>1)*65536)
//      when AMODE==5) | 4 fused P|S (bz==0 -> Pb2 hi|lo; bz==1 -> A=Pprev,
//      Sb2 hi|lo + slope norms).
template<int BM, int BN, int AMODE, int SECSH, int EPI, int BMODE, typename OUT_T>
__global__ __launch_bounds__(256) void gemm_bt_k(
    const void* __restrict__ Av, const _Float16* __restrict__ BT,
    OUT_T* __restrict__ C, int K, int lda, int ldb, int ldc,
    long sAb, long sAh, long sBb, long sBh, long sCb, long sCh,
    const float* __restrict__ norms, const float* __restrict__ scp,
    const float* __restrict__ ofp, const float* __restrict__ Pprev,
    float* __restrict__ nout)
{
  __shared__ __align__(16) _Float16 sA[BM * 64];
  __shared__ __align__(16) _Float16 sB[BN * 64];
  const int t = threadIdx.x;
  const int lane = t & 63;
  const int w = t >> 6;
  const int wm = w >> 1, wn = w & 1;
  const int by = blockIdx.x, bx = blockIdx.y, bz = blockIdx.z;
  long aoff64 = (long)(bz >> 4) * sAb + (long)(bz & 15) * sAh;
  if constexpr (AMODE == 5) aoff64 = (long)(bz >> 1) * sAh;  // bb stride
  const _Float16* BT16 = BT;
  const float*    B32  = (const float*)BT;
  if constexpr (BMODE == 0) BT16 += (long)(bz >> 4) * sBb + (long)(bz & 15) * sBh;
  else                      B32  += (long)(bz >> 4) * sBb + (long)(bz & 15) * sBh;
  C += (long)(bz >> 4) * sCb + (long)(bz & 15) * sCh;
  const _Float16* A16 = (const _Float16*)Av + aoff64;
  if constexpr (EPI == 4) {               // fused P|S: z=1 reads slopes side
    if (bz & 15) A16 = (const _Float16*)Pprev + aoff64;
  }
  constexpr int WTM = BM / 32, WTN = BN / 32;
  fx4 acc[WTM][WTN];
#pragma unroll
  for (int i = 0; i < WTM; ++i)
#pragma unroll
    for (int j = 0; j < WTN; ++j) acc[i][j] = (fx4){0.f, 0.f, 0.f, 0.f};

  // ---- hoisted 32-bit staging offsets (k0-invariant) ----
  const int trow = t >> 3;                     // 0..31
  const int kc8  = ((t & 7) ^ (trow & 7)) * 8; // element offset within row
  int aoff[BM / 32];
#pragma unroll
  for (int i = 0; i < BM / 32; ++i)
    aoff[i] = (by * BM + i * 32 + trow) * lda + kc8;
  int boff[BN / 32];
#pragma unroll
  for (int i = 0; i < BN / 32; ++i)
    boff[i] = (bx * BN + i * 32 + trow) * ldb + kc8;
  // LDS dest slots (wave-uniform base per i; HW adds lane*16)
  _Float16* sAdst[BM / 32];
  _Float16* sBdst[BN / 32];
#pragma unroll
  for (int i = 0; i < BM / 32; ++i) sAdst[i] = &sA[(i * 256 + (w << 6)) * 8];
#pragma unroll
  for (int i = 0; i < BN / 32; ++i) sBdst[i] = &sB[(i * 256 + (w << 6)) * 8];

  int Klim = K;
  if constexpr (AMODE == 5) { if ((bz & 1) == 0) Klim >>= 1; }

  for (int k0 = 0; k0 < Klim; k0 += 64) {
    __syncthreads();
    // ---- stage A tile [BM x 64] via global_load_lds (saddr + 32b voffset) --
    {
      int cb;
      if constexpr (AMODE == 4) {
        int sec = k0 >> SECSH;
        cb = (k0 & ((1 << SECSH) - 1)) + (sec == 1 ? (1 << SECSH) : 0);
      } else if constexpr (AMODE == 5) {
        int sec = k0 >> SECSH;
        cb = ((sec == 1 || sec == 4) ? 64 : 0) + (sec >= 3 ? (int)sAb : 0);
      } else cb = k0;
#pragma unroll
      for (int i = 0; i < BM / 32; ++i) g2l16(A16 + (aoff[i] + cb), sAdst[i]);
    }
    // ---- stage B tile [BN x 64] ----
    if constexpr (BMODE == 0) {
#pragma unroll
      for (int i = 0; i < BN / 32; ++i) g2l16(BT16 + (boff[i] + k0), sBdst[i]);
    } else {
#pragma unroll
      for (int i = 0; i < BN / 32; ++i) {
        const float* src = B32 + (boff[i] + k0);
        fx4 v0 = *(const fx4*)src;
        fx4 v1 = *(const fx4*)(src + 4);
        hx8 hv;
#pragma unroll
        for (int e = 0; e < 4; ++e) { hv[e] = (_Float16)v0[e]; hv[4 + e] = (_Float16)v1[e]; }
        *(hx8*)&sB[(i * 256 + t) * 8] = hv;
      }
    }
    __syncthreads();
#pragma unroll
    for (int kk = 0; kk < 64; kk += 32) {
      hx8 af[WTM], bf[WTN];
      int kcb = (kk >> 3) + (lane >> 4);
#pragma unroll
      for (int i = 0; i < WTM; ++i) {
        int r = wm * (BM / 2) + i * 16 + (lane & 15);
        af[i] = *(const hx8*)&sA[(r * 8 + (kcb ^ (r & 7))) * 8];
      }
#pragma unroll
      for (int j = 0; j < WTN; ++j) {
        int r = wn * (BN / 2) + j * 16 + (lane & 15);
        bf[j] = *(const hx8*)&sB[(r * 8 + (kcb ^ (r & 7))) * 8];
      }
#pragma unroll
      for (int i = 0; i < WTM; ++i)
#pragma unroll
        for (int j = 0; j < WTN; ++j)
          acc[i][j] = __builtin_amdgcn_mfma_f32_16x16x32_f16(af[i], bf[j], acc[i][j], 0, 0, 0);
    }
  }
  if constexpr (EPI == 0) {
#pragma unroll
    for (int i = 0; i < WTM; ++i) {
#pragma unroll
      for (int j = 0; j < WTN; ++j) {
        int rowb = by * BM + wm * (BM / 2) + i * 16 + ((lane >> 4) << 2);
        int col  = bx * BN + wn * (BN / 2) + j * 16 + (lane & 15);
#pragma unroll
        for (int r = 0; r < 4; ++r)
          C[(long)(rowb + r) * ldc + col] = (OUT_T)acc[i][j][r];
      }
    }
  } else if constexpr (EPI == 1) {
    const float inv2pi = 0.15915494309189535f;
    const float ratio  = 0.08838834764831845f;   // 1/sqrt(128)
    const bool useN = ((bz & 1) == 0);
    const float* nrm = norms;
    if constexpr (AMODE == 5) nrm += (long)(bz >> 1) * 65536;
#pragma unroll
    for (int i = 0; i < WTM; ++i) {
#pragma unroll
      for (int j = 0; j < WTN; ++j) {
        int rowb = by * BM + wm * (BM / 2) + i * 16 + ((lane >> 4) << 2);
        int col  = bx * BN + wn * (BN / 2) + j * 16 + (lane & 15);
#pragma unroll
        for (int r = 0; r < 4; ++r) {
          int row = rowb + r;                     // row = l*16 + h
          float rn = ratio * (useN ? nrm[row] : 1.0f);
          long ob = ((long)(row & 15) * 4096 + (row >> 4)) * 256;
          float v = acc[i][j][r] * inv2pi;
          v -= floorf(v);                         // revolutions in [0,1)
          C[ob + col]       = (OUT_T)(rn * __builtin_amdgcn_sinf(v));
          C[ob + 128 + col] = (OUT_T)(rn * __builtin_amdgcn_cosf(v));
        }
      }
    }
  } else {                                // EPI == 4: fused P|S, f16 hi|lo out
    const int h = ((bx * BN) >> 6) + wn;  // BN=128: 2 heads/block, wave-uniform
    const float sc = scp[h];
    _Float16* C16 = (_Float16*)C;
    if ((bz & 15) == 0) {                 // P: Pb2 = hi|lo of scale*acc
#pragma unroll
      for (int i = 0; i < WTM; ++i) {
#pragma unroll
        for (int j = 0; j < WTN; ++j) {
          int rowb = by * BM + wm * (BM / 2) + i * 16 + ((lane >> 4) << 2);
          int d    = j * 16 + (lane & 15);
#pragma unroll
          for (int r = 0; r < 4; ++r) {
            float v = sc * acc[i][j][r];
            long a = ((long)(rowb + r) * 16 + h) * 128 + d;
            _Float16 hi = (_Float16)v;
            C16[a]      = hi;
            C16[a + 64] = (_Float16)(v - (float)hi);
          }
        }
      }
    } else {                              // S: Sb2 = hi|lo of offs*scale*acc
      const float osc = ofp[h] * sc;
#pragma unroll
      for (int i = 0; i < WTM; ++i) {
        float sq[4] = {0.f, 0.f, 0.f, 0.f};
        int rowb = by * BM + wm * (BM / 2) + i * 16 + ((lane >> 4) << 2);
#pragma unroll
        for (int j = 0; j < WTN; ++j) {
          int d = j * 16 + (lane & 15);
#pragma unroll
          for (int r = 0; r < 4; ++r) {
            float a0 = acc[i][j][r];
            sq[r] += a0 * a0;
            float v = osc * a0;
            long a = ((long)(rowb + r) * 16 + h) * 128 + d;
            _Float16 hi = (_Float16)v;
            C16[a]      = hi;
            C16[a + 64] = (_Float16)(v - (float)hi);
          }
        }
#pragma unroll
        for (int r = 0; r < 4; ++r) {     // 64-col norm: 4 j's x 16 lanes
          float s = sq[r];
          s += __shfl_xor(s, 1); s += __shfl_xor(s, 2);
          s += __shfl_xor(s, 4); s += __shfl_xor(s, 8);
          if ((lane & 15) == 0)
            nout[(long)(rowb + r) * 16 + h] = sqrtf(s) * (1.0f / 4096.0f);
        }
      }
    }
  }
}

// ---------------- kv kernel: kvT[d][m] = sum_l v[l][d] * k'[l][m] ----------
// blockIdx.z = bb (batched); strides passed explicitly (0 for single-b).
// Staging: 4x8 register transpose -> ds_write_b64, XOR bank-swizzle.
__global__ __launch_bounds__(256) void kv_k(const _Float16* __restrict__ Kp,
                                            const _Float16* __restrict__ Vhb,
                                            float* __restrict__ kvacc,
                                            long kstride, long vstride,
                                            long ostride)
{
  __shared__ __align__(16) _Float16 sK[256 * 72];   // [m][l] stride 72, swizzled
  __shared__ __align__(16) _Float16 sV[64 * 72];    // [d][l]
  const int t = threadIdx.x, lane = t & 63, w = t >> 6;
  const int h = blockIdx.x;
  const int l0 = blockIdx.y * (L_ / KV_SPLIT);
  const int bb = blockIdx.z;
  Kp    += (long)bb * kstride;
  Vhb   += (long)bb * vstride;
  kvacc += (long)bb * ostride;
  fx4 acc[4][4];
#pragma unroll
  for (int i = 0; i < 4; ++i)
#pragma unroll
    for (int j = 0; j < 4; ++j) acc[i][j] = (fx4){0.f, 0.f, 0.f, 0.f};
  const _Float16* Kbase = Kp + (long)h * L_ * 256;
  for (int kt = 0; kt < L_ / KV_SPLIT; kt += 64) {
    __syncthreads();
    // k' tile: 64 l x 256 m. 512 items (m8, l4), 2 per thread.
#pragma unroll
    for (int it = 0; it < 2; ++it) {
      int idx = t + it * 256;
      int m8 = idx & 31, bl = (idx >> 5) << 2;
      const _Float16* src = &Kbase[(long)(l0 + kt + bl) * 256 + m8 * 8];
      hx8 r0 = *(const hx8*)(src);
      hx8 r1 = *(const hx8*)(src + 256);
      hx8 r2 = *(const hx8*)(src + 512);
      hx8 r3 = *(const hx8*)(src + 768);
      int kx = (m8 & 7) << 4;
#pragma unroll
      for (int e = 0; e < 8; ++e) {
        hx4 v; v[0] = r0[e]; v[1] = r1[e]; v[2] = r2[e]; v[3] = r3[e];
        int byte = (((m8 * 8 + e) * 72 + bl) * 2) ^ kx;
        *(hx4*)((char*)sK + byte) = v;
      }
    }
    // v tile: 64 l x 64 d. 128 items, threads t<128.
    if (t < 128) {
      int d8 = t & 7, bl = (t >> 3) << 2;
      const _Float16* src = &Vhb[(long)(l0 + kt + bl) * 1024 + h * 64 + d8 * 8];
      hx8 r0 = *(const hx8*)(src);
      hx8 r1 = *(const hx8*)(src + 1024);
      hx8 r2 = *(const hx8*)(src + 2048);
      hx8 r3 = *(const hx8*)(src + 3072);
      int kx = d8 << 4;
#pragma unroll
      for (int e = 0; e < 8; ++e) {
        hx4 v; v[0] = r0[e]; v[1] = r1[e]; v[2] = r2[e]; v[3] = r3[e];
        int byte = (((d8 * 8 + e) * 72 + bl) * 2) ^ kx;
        *(hx4*)((char*)sV + byte) = v;
      }
    }
    __syncthreads();
#pragma unroll
    for (int kk = 0; kk < 64; kk += 32) {
      hx8 af[4], bf[4];
      int lfr = kk + ((lane >> 4) << 3);
#pragma unroll
      for (int i = 0; i < 4; ++i) {
        int r = i * 16 + (lane & 15);
        af[i] = *(const hx8*)((const char*)sV +
                ((((r * 72 + lfr) * 2)) ^ (((r >> 3) & 7) << 4)));
      }
#pragma unroll
      for (int j = 0; j < 4; ++j) {
        int r = w * 64 + j * 16 + (lane & 15);
        bf[j] = *(const hx8*)((const char*)sK +
                ((((r * 72 + lfr) * 2)) ^ (((r >> 3) & 7) << 4)));
      }
#pragma unroll
      for (int i = 0; i < 4; ++i)
#pragma unroll
        for (int j = 0; j < 4; ++j)
          acc[i][j] = __builtin_amdgcn_mfma_f32_16x16x32_f16(af[i], bf[j], acc[i][j], 0, 0, 0);
    }
  }
  float* obase = kvacc + (long)h * (64 * 256);
#pragma unroll
  for (int i = 0; i < 4; ++i)
#pragma unroll
    for (int j = 0; j < 4; ++j) {
      int d0 = i * 16 + ((lane >> 4) << 2);
      int m  = w * 64 + j * 16 + (lane & 15);
#pragma unroll
      for (int r = 0; r < 4; ++r)
        atomicAdd(&obase[(long)(d0 + r) * 256 + m], acc[i][j][r]);
    }
}

// ---------------------------------------------------------------------------
extern "C" void kernel_launch(void* const* d_in, const int* in_sizes, int n_in,
                              void* d_out, int out_size, void* d_ws, size_t ws_size,
                              hipStream_t stream) {
  const float* x     = (const float*)d_in[0];
  const float* pos   = (const float*)d_in[1];
  const float* slp   = (const float*)d_in[2];
  const float* Wv    = (const float*)d_in[3];
  const float* Wo    = (const float*)d_in[4];
  const float* Wpf   = (const float*)d_in[5];
  const float* scale = (const float*)d_in[6];
  const float* offs  = (const float*)d_in[7];
  const float* proj  = (const float*)d_in[8];
  float* out = (float*)d_out;
  char* ws = (char*)d_ws;

  // Arena. Batched path needs qpr region x2 (134MB, ~284MB total); gated on
  // ws_size with per-bb fallback (~217MB). Aliases: ph2/sh2 live in the qpr
  // region (dead before fourier writes it); xh = Zb (dead after V).
  // Sb2 must follow Pb2 contiguously (+16777216 f16).
  size_t o = 0;
  auto alloc = [&](size_t bytes) { char* p = ws + o; o += (bytes + 255) & ~(size_t)255; return p; };
  _Float16* Pb2 = (_Float16*)alloc(33554432);   // [2bb][65536 lh][128 hi|lo]
  _Float16* Sb2 = (_Float16*)alloc(33554432);   //   == Pb2 + 16777216 elems
  const size_t rest = 33554432UL * 2 + 2097152UL * 2 + 6291456 + 98304 + 524288 + 4194304;
  const bool batched = ws_size >= o + 134217728UL + rest + 8192;
  _Float16* qpr = (_Float16*)alloc(batched ? 134217728UL : 67108864UL);
  // batched: [bb][q 16.7M | k 16.7M] elems; else: [q 16.7M | k 16.7M]
  _Float16* Vh     = (_Float16*)alloc(33554432);   // [BL][1024] f16
  _Float16* Zb     = (_Float16*)alloc(33554432);   // [BL][1024] f16
  _Float16* WvT    = (_Float16*)alloc(2097152);
  _Float16* WoT    = (_Float16*)alloc(2097152);
  _Float16* Wpf3T  = (_Float16*)alloc(6291456);    // [1024][3072] [hi;hi;lo]
  _Float16* proj6T = (_Float16*)alloc(98304);      // [128][384]
  float*    normsB = (float*)alloc(524288);        // [8192][16] f32 per sb
  float*    kvacc  = (float*)alloc(4194304);       // [BH][64][256] f32
  _Float16* ph2 = qpr;                             // [8192][2048] f16 [hi|lo]
  _Float16* sh2 = qpr + 16777216;
  _Float16* xh  = Zb;                              // [16384][1024] f16
  (void)Sb2; (void)in_sizes; (void)n_in; (void)out_size;

  // prep: all weight transforms + kvacc zero + x->f16 in ONE launch
  prep_k<<<9248, 256, 0, stream>>>(Wv, WvT, Wo, WoT, Wpf, Wpf3T, proj, proj6T,
                                   kvacc, x, xh);

  // V = xh @ W_v (pure f16, gload_lds staging), M=16384
  gemm_bt_k<128, 128, 0, 0, 0, 0, _Float16><<<dim3(128, 8, 1), 256, 0, stream>>>(
      xh, WvT, Vh, 1024, 1024, 1024, 1024, 0, 0, 0, 0, 0, 0,
      nullptr, nullptr, nullptr, nullptr, nullptr);

  for (int sb = 0; sb < 2; ++sb) {
    const float* pos_sb = pos + (long)sb * 8192 * 1024;
    const float* slp_sb = slp + (long)sb * 8192 * 1024;
    _Float16* Vh_sb = Vh + (long)sb * 2 * L_ * 1024;
    _Float16* Zb_sb = Zb + (long)sb * 2 * L_ * 1024;
    float* kvacc_sb = kvacc + (long)sb * 2 * 262144;

    // pre-split pos+slp to f16 [hi|lo] in one launch
    cvt_hilo2_k<<<dim3(4096, 2), 256, 0, stream>>>(pos_sb, slp_sb, ph2, sh2);
    // Fused P|S: z=0 -> Pb2 = hilo(scale*(pos@W)); z=1 -> Sb2 =
    // hilo(offs*scale*(slp@W)) + slope norms. AMODE=4, virtual K=3072.
    gemm_bt_k<128, 128, 4, 10, 4, 0, _Float16><<<dim3(64, 8, 2), 256, 0, stream>>>(
        ph2, Wpf3T, Pb2, 3072, 2048, 3072, 128, 0, 0, 0, 0, 0, 16777216L,
        nullptr, scale, offs, (const float*)sh2, normsB);

    if (batched) {
      // fourier both bb: z=4 (bz>>1 = bb via sAh/sCh, bz&1 = q/k).
      // C += bz*16777216 covers {bb0 q, bb0 k, bb1 q, bb1 k} exactly.
      gemm_bt_k<128, 128, 5, 6, 1, 0, _Float16><<<dim3(512, 1, 4), 256, 0, stream>>>(
          Pb2, proj6T, qpr, 384, 128, 384, 0,
          16777216L /*S offset*/, 8388608L /*bb A-stride*/, 0, 0, 0, 16777216L,
          normsB, nullptr, nullptr, nullptr, nullptr);
      // kv both bb: z=2; k' at qpr + bb*33.5M + 16.7M
      kv_k<<<dim3(16, KV_SPLIT, 2), 256, 0, stream>>>(
          qpr + 16777216, Vh_sb, kvacc_sb, 33554432L, 4194304L, 262144L);
      // z both bb: z=32 (bz>>4 = bb, bz&15 = h); B from f32 kvacc
      gemm_bt_k<128, 64, 0, 0, 0, 1, _Float16><<<dim3(32, 1, 32), 256, 0, stream>>>(
          qpr, (const _Float16*)kvacc_sb, Zb_sb, 256, 256, 256, 1024,
          33554432L, (long)L_ * 256, 262144L, 16384L, (long)L_ * 1024, 64L,
          nullptr, nullptr, nullptr, nullptr, nullptr);
    } else {
      for (int bb = 0; bb < 2; ++bb) {
        _Float16* Vh_b  = Vh_sb + (long)bb * L_ * 1024;
        _Float16* Zb_b  = Zb_sb + (long)bb * L_ * 1024;
        float* kvacc_b  = kvacc_sb + (long)bb * 262144;
        gemm_bt_k<128, 128, 5, 6, 1, 0, _Float16><<<dim3(512, 1, 2), 256, 0, stream>>>(
            Pb2 + (long)bb * 8388608, proj6T, qpr, 384, 128, 384, 0,
            16777216L, 0L, 0, 0, 0, 16777216L,
            normsB + (long)bb * 65536, nullptr, nullptr, nullptr, nullptr);
        kv_k<<<dim3(16, KV_SPLIT, 1), 256, 0, stream>>>(
            qpr + 16777216, Vh_b, kvacc_b, 0L, 0L, 0L);
        gemm_bt_k<128, 64, 0, 0, 0, 1, _Float16><<<dim3(32, 1, 16), 256, 0, stream>>>(
            qpr, (const _Float16*)kvacc_b, Zb_b, 256, 256, 256, 1024,
            0L, (long)L_ * 256, 0L, 16384L, 0L, 64L,
            nullptr, nullptr, nullptr, nullptr, nullptr);
      }
    }
  }
  // out = z @ W_o (f32 out), M=16384
  gemm_bt_k<128, 128, 0, 0, 0, 0, float><<<dim3(128, 8, 1), 256, 0, stream>>>(
      Zb, WoT, out, 1024, 1024, 1024, 1024, 0, 0, 0, 0, 0, 0,
      nullptr, nullptr, nullptr, nullptr, nullptr);
}